// Round 1
// baseline (6489.022 us; speedup 1.0000x reference)
//
#include <hip/hip_runtime.h>
#include <math.h>

#define D       128
#define KCODES  1024
#define NQ      8
#define BATCH   8
#define SLEN    4096
#define NPTS    (BATCH*SLEN)     /* 32768 */
#define TM      64               /* points per argmin block */

// ---------------- zero scratch ----------------
__global__ void k_zero(int* hist, double* csum) {
    int t = blockIdx.x * blockDim.x + threadIdx.x;
    if (t < NQ * KCODES) hist[t] = 0;
    if (t == 0) *csum = 0.0;
}

// ---------------- codebook norms: numpy pairwise fp32 ----------------
__global__ void k_c2(const float* __restrict__ cbs, float* __restrict__ c2f) {
    int i = blockIdx.x * blockDim.x + threadIdx.x;   // 0..8191
    const float* row = cbs + (size_t)i * D;
    float r8[8];
    #pragma unroll
    for (int j = 0; j < 8; ++j) r8[j] = __fmul_rn(row[j], row[j]);
    for (int d = 8; d < 128; d += 8)
        #pragma unroll
        for (int j = 0; j < 8; ++j)
            r8[j] = __fadd_rn(r8[j], __fmul_rn(row[d + j], row[d + j]));
    float s01 = __fadd_rn(r8[0], r8[1]);
    float s23 = __fadd_rn(r8[2], r8[3]);
    float s45 = __fadd_rn(r8[4], r8[5]);
    float s67 = __fadd_rn(r8[6], r8[7]);
    c2f[i] = __fadd_rn(__fadd_rn(s01, s23), __fadd_rn(s45, s67));
}

// ---------------- init: z [B,D,S] -> resid fp32 [n][d]; quant = 0 ----------------
__global__ __launch_bounds__(256) void k_init(const float* __restrict__ z,
                                              float* __restrict__ resid,
                                              float* __restrict__ quant) {
    __shared__ float xt[64][129];
    int b = blockIdx.x >> 6, st = blockIdx.x & 63;
    int s0 = st * 64;
    for (int it = 0; it < 32; ++it) {
        int flat = it * 256 + threadIdx.x;
        int d = flat >> 6, sl = flat & 63;
        xt[sl][d] = z[((size_t)(b * D + d)) * SLEN + s0 + sl];
    }
    __syncthreads();
    for (int it = 0; it < 8; ++it) {
        int flat = it * 256 + threadIdx.x;
        int sl = flat >> 5, dq = (flat & 31) * 4;
        size_t o = (size_t)(b * SLEN + s0 + sl) * D + dq;
        float4 r;
        r.x = xt[sl][dq]; r.y = xt[sl][dq + 1];
        r.z = xt[sl][dq + 2]; r.w = xt[sl][dq + 3];
        *(float4*)(resid + o) = r;
        float4 zz; zz.x = zz.y = zz.z = zz.w = 0.0f;
        *(float4*)(quant + o) = zz;
    }
}

// ---------------- fp32-emulated argmin (matches numpy/BLAS rounding) ----------------
// Barrier-free wave-private schedule. 256 thr = 4 waves; wave w owns codes
// [w*256, w*256+256) in 4 chunks of 64. Lanes: pl = l&7 (point group),
// cl = l>>3 (code group). Per-thread tile 8 pts x 8 codes (acc[8][8]).
// K sliced 16 dims/step, reg-staged (load-early / write-late) into a
// per-wave 2x4KB LDS ring with XOR-swizzled layout:
//   slice row k (64B) stores dim-chunk d at position p = d ^ ((k>>1)&3)
// -> every cf ds_read_b128 hits 8 distinct bank groups (conflict-free).
// Exact fp32 semantics: k-ascending single-FMA chain per (point,code),
// score fl(fl(xx - 2*acc) + cc), first-min (strict <, k ascending).
__global__ __launch_bounds__(256, 2) void k_argmin(const float* __restrict__ cb,
                                                   const float* __restrict__ c2,
                                                   const float* __restrict__ resid,
                                                   int* __restrict__ idx_out) {
    __shared__ __align__(16) float xs[TM][132];     // 33,792 B
    __shared__ float xxs[TM];
    __shared__ __align__(16) float cs[4][2][1024];  // 32,768 B: [wave][buf][64c x 16d]
    __shared__ float redS[4][TM];
    __shared__ int   redI[4][TM];

    int tid = threadIdx.x;
    int pbase = blockIdx.x * TM;
    int l = tid & 63, w = tid >> 6;
    int pl = l & 7, cl = l >> 3;

    const char*  cwb = (const char*)cb + ((size_t)w << 17);  // wave's 256 code rows
    const float* c2w = c2 + (w << 8);

    // per-lane global source offset within one (chunk,slice,g) unit:
    // row (l>>2)+16g (g adds 8192B), dim-chunk l&3 of the 64B slice row
    int gsrc_lane = ((l >> 2) << 9) + ((l & 3) << 4);
    // per-lane LDS write offset (bytes within wave-buf): row l>>2 (+16g),
    // swizzled position (l&3) ^ tau, tau = (l>>3)&3 == ((16g+(l>>2))>>1)&3
    int wtau  = (l >> 3) & 3;
    int wunit = ((l >> 2) << 6) + (((l & 3) ^ wtau) << 4);
    // per-lane cf read swizzle: row k'=cl+8j -> tau_row = (cl>>1)&3
    int rtau = (cl >> 1) & 3;
    char* csw = (char*)&cs[w][0][0];

    // prologue: issue slice 0 (chunk 0, s=0) loads, hidden under X staging
    float4 pre[4];
    #pragma unroll
    for (int g = 0; g < 4; ++g)
        pre[g] = *(const float4*)(cwb + gsrc_lane + (g << 13));

    // stage X tile (fp32 residual), coalesced float4
    #pragma unroll
    for (int it = 0; it < 8; ++it) {
        int e = (it * 256 + tid) * 4;
        int p = e >> 7, d = e & 127;
        *(float4*)&xs[p][d] = *(const float4*)(resid + (size_t)(pbase + p) * D + d);
    }
    __syncthreads();

    // xx per point: numpy pairwise n=128 (8-accumulator pattern)
    if (tid < TM) {
        float r8[8];
        #pragma unroll
        for (int j = 0; j < 8; ++j) r8[j] = __fmul_rn(xs[tid][j], xs[tid][j]);
        for (int i = 8; i < 128; i += 8)
            #pragma unroll
            for (int j = 0; j < 8; ++j)
                r8[j] = __fadd_rn(r8[j], __fmul_rn(xs[tid][i + j], xs[tid][i + j]));
        float s01 = __fadd_rn(r8[0], r8[1]);
        float s23 = __fadd_rn(r8[2], r8[3]);
        float s45 = __fadd_rn(r8[4], r8[5]);
        float s67 = __fadd_rn(r8[6], r8[7]);
        xxs[tid] = __fadd_rn(__fadd_rn(s01, s23), __fadd_rn(s45, s67));
    }
    __syncthreads();

    float xxr[8];
    #pragma unroll
    for (int i = 0; i < 8; ++i) xxr[i] = xxs[pl + 8 * i];

    float acc[8][8];
    #pragma unroll
    for (int i = 0; i < 8; ++i)
        #pragma unroll
        for (int j = 0; j < 8; ++j) acc[i][j] = 0.0f;
    float best[8]; int bidx[8];
    #pragma unroll
    for (int i = 0; i < 8; ++i) { best[i] = 3.4e38f; bidx[i] = 0; }

    // write slice 0 into buf 0 (compiler inserts the vmcnt wait)
    #pragma unroll
    for (int g = 0; g < 4; ++g)
        *(float4*)(csw + wunit + (g << 10)) = pre[g];

    float cc8[8];
    for (int t = 0; t < 32; ++t) {           // t = chunk*8 + slice
        int cblk = t >> 3, s = t & 7, buf = t & 1;
        if (s == 0) {
            #pragma unroll
            for (int j = 0; j < 8; ++j)
                cc8[j] = c2w[(cblk << 6) + cl + (j << 3)];
        }
        if (t < 31) {                        // issue next slice's loads EARLY
            int t2 = t + 1, cb2 = t2 >> 3, s2 = t2 & 7;
            const char* src = cwb + gsrc_lane + (cb2 << 15) + (s2 << 6);
            #pragma unroll
            for (int g = 0; g < 4; ++g)
                pre[g] = *(const float4*)(src + (g << 13));
        }
        // compute slice t from buf (t&1): 4 d4-steps x 256 FMA
        const char* cbuf = csw + (buf << 12) + cl * 64;
        const char* xrow = (const char*)&xs[0][0] + pl * 528 + (s << 6);
        #pragma unroll
        for (int d4 = 0; d4 < 4; ++d4) {
            float4 xf[8], cf[8];
            #pragma unroll
            for (int i = 0; i < 8; ++i)
                xf[i] = *(const float4*)(xrow + i * 4224 + (d4 << 4));
            #pragma unroll
            for (int j = 0; j < 8; ++j)
                cf[j] = *(const float4*)(cbuf + ((d4 ^ rtau) << 4) + (j << 9));
            #pragma unroll
            for (int j = 0; j < 8; ++j)
                #pragma unroll
                for (int i = 0; i < 8; ++i) {
                    acc[i][j] = __fmaf_rn(xf[i].x, cf[j].x, acc[i][j]);
                    acc[i][j] = __fmaf_rn(xf[i].y, cf[j].y, acc[i][j]);
                    acc[i][j] = __fmaf_rn(xf[i].z, cf[j].z, acc[i][j]);
                    acc[i][j] = __fmaf_rn(xf[i].w, cf[j].w, acc[i][j]);
                }
        }
        if (t < 31) {                        // write next slice LATE (into other buf)
            char* wb = csw + ((~t & 1) << 12);
            #pragma unroll
            for (int g = 0; g < 4; ++g)
                *(float4*)(wb + wunit + (g << 10)) = pre[g];
        }
        if (s == 7) {                        // end of chunk: fold scores
            #pragma unroll
            for (int j = 0; j < 8; ++j) {
                float cc = cc8[j];
                int k = (w << 8) + (cblk << 6) + cl + (j << 3);
                #pragma unroll
                for (int i = 0; i < 8; ++i) {
                    float t1  = __fadd_rn(xxr[i],
                                          __fmul_rn(-2.0f, acc[i][j]));
                    float dsc = __fadd_rn(t1, cc);
                    if (dsc < best[i]) { best[i] = dsc; bidx[i] = k; }  // k ascending
                    acc[i][j] = 0.0f;
                }
            }
        }
    }

    // cross-lane (cl bits 3..5) lexicographic argmin reduce, then cross-wave
    #pragma unroll
    for (int i = 0; i < 8; ++i) {
        float b = best[i]; int bi = bidx[i];
        #pragma unroll
        for (int off = 8; off < 64; off <<= 1) {
            float b2 = __shfl_xor(b, off, 64);
            int  bi2 = __shfl_xor(bi, off, 64);
            if (b2 < b || (b2 == b && bi2 < bi)) { b = b2; bi = bi2; }
        }
        if (cl == 0) { redS[w][pl + 8 * i] = b; redI[w][pl + 8 * i] = bi; }
    }
    __syncthreads();
    if (tid < TM) {
        float b = redS[0][tid]; int bi = redI[0][tid];
        #pragma unroll
        for (int ww = 1; ww < 4; ++ww) {
            float b2 = redS[ww][tid]; int bi2 = redI[ww][tid];
            if (b2 < b || (b2 == b && bi2 < bi)) { b = b2; bi = bi2; }
        }
        idx_out[pbase + tid] = bi;
    }
}

// ---------------- residual/quant update (fp32, exact np order) ----------------
__global__ void k_update(const float* __restrict__ cb, const int* __restrict__ idx,
                         float* __restrict__ resid, float* __restrict__ quant) {
    int gid = blockIdx.x * blockDim.x + threadIdx.x;   // NPTS*32
    int n = gid >> 5, d4 = (gid & 31) * 4;
    int k = idx[n];
    float4 c = *(const float4*)(cb + (size_t)k * D + d4);
    size_t o = (size_t)n * D + d4;
    float4 r = *(const float4*)(resid + o);
    float4 q = *(const float4*)(quant + o);
    r.x = __fsub_rn(r.x, c.x); r.y = __fsub_rn(r.y, c.y);
    r.z = __fsub_rn(r.z, c.z); r.w = __fsub_rn(r.w, c.w);
    q.x = __fadd_rn(q.x, c.x); q.y = __fadd_rn(q.y, c.y);
    q.z = __fadd_rn(q.z, c.z); q.w = __fadd_rn(q.w, c.w);
    *(float4*)(resid + o) = r;
    *(float4*)(quant + o) = q;
}

// ---------------- out0 = fl(z + fl(q - z)) transposed; commitment partial ----------------
__global__ __launch_bounds__(256) void k_out0(const float* __restrict__ z,
                                              const float* __restrict__ quant,
                                              float* __restrict__ out0,
                                              double* __restrict__ csum) {
    __shared__ float xt[64][129];
    __shared__ double wsum[4];
    int b = blockIdx.x >> 6, st = blockIdx.x & 63;
    int s0 = st * 64;
    for (int it = 0; it < 8; ++it) {
        int flat = it * 256 + threadIdx.x;
        int sl = flat >> 5, dq = (flat & 31) * 4;
        float4 q = *(const float4*)(quant + (size_t)(b * SLEN + s0 + sl) * D + dq);
        xt[sl][dq] = q.x; xt[sl][dq + 1] = q.y;
        xt[sl][dq + 2] = q.z; xt[sl][dq + 3] = q.w;
    }
    __syncthreads();
    double v = 0.0;
    for (int it = 0; it < 32; ++it) {
        int flat = it * 256 + threadIdx.x;
        int d = flat >> 6, sl = flat & 63;
        size_t o = ((size_t)(b * D + d)) * SLEN + s0 + sl;
        float zz = z[o], qq = xt[sl][d];
        out0[o] = __fadd_rn(zz, __fsub_rn(qq, zz));
        float e = __fsub_rn(zz, qq);
        v += (double)e * (double)e;
    }
    for (int off = 32; off > 0; off >>= 1) v += __shfl_down(v, off, 64);
    int lane = threadIdx.x & 63, wv = threadIdx.x >> 6;
    if (lane == 0) wsum[wv] = v;
    __syncthreads();
    if (threadIdx.x == 0) {
        double tsum = wsum[0] + wsum[1] + wsum[2] + wsum[3];
        atomicAdd(csum, tsum);
    }
}

// ---------------- indices output as float ----------------
__global__ void k_outidx(const int* __restrict__ idx, float* __restrict__ out1) {
    int o = blockIdx.x * blockDim.x + threadIdx.x;   // NPTS*NQ
    int q = o & 7, n = o >> 3;
    out1[o] = (float)idx[q * NPTS + n];
}

// ---------------- histogram ----------------
__global__ void k_hist(const int* __restrict__ idx, int* __restrict__ hist) {
    int o = blockIdx.x * blockDim.x + threadIdx.x;   // NQ*NPTS (layout [q][n])
    int q = o >> 15;
    atomicAdd(&hist[q * KCODES + idx[o]], 1);
}

// ---------------- final scalars ----------------
__global__ __launch_bounds__(256) void k_final(const int* __restrict__ hist,
                                               const double* __restrict__ csum,
                                               float* __restrict__ outs) {
    __shared__ double sh[256];
    double perp = 0.0;
    for (int q = 0; q < NQ; ++q) {
        double h = 0.0;
        for (int k = threadIdx.x; k < KCODES; k += 256) {
            double p = (double)hist[q * KCODES + k] / (double)NPTS;
            h -= p * log(p + 1e-10);
        }
        sh[threadIdx.x] = h; __syncthreads();
        for (int off = 128; off > 0; off >>= 1) {
            if (threadIdx.x < off) sh[threadIdx.x] += sh[threadIdx.x + off];
            __syncthreads();
        }
        if (threadIdx.x == 0) perp += exp(sh[0]);
        __syncthreads();
    }
    if (threadIdx.x == 0) {
        outs[0] = (float)(*csum / (double)((size_t)NPTS * D));
        outs[1] = (float)(perp / (double)NQ);
    }
}

extern "C" void kernel_launch(void* const* d_in, const int* in_sizes, int n_in,
                              void* d_out, int out_size, void* d_ws, size_t ws_size,
                              hipStream_t stream) {
    const float* z  = (const float*)d_in[0];
    const float* cb = (const float*)d_in[1];
    float* out0 = (float*)d_out;                 // 4,194,304 floats [B,D,S]
    float* out1 = out0 + 4194304;                // 262,144 floats  [B,S,Q]
    float* outs = out1 + 262144;                 // 2 scalars

    char* w = (char*)d_ws;
    float* resid  = (float*)w;                           // 16,777,216 B
    float* quant  = (float*)(w + 16777216);              // 16,777,216 B
    int*   idx    = (int*)(w + 33554432);                //  1,048,576 B
    int*   hist   = (int*)(w + 34603008);                //     32,768 B
    double* csum  = (double*)(w + 34635776);             //         64 B
    float* c2f    = (float*)(w + 34635840);              //     32,768 B

    k_zero<<<32, 256, 0, stream>>>(hist, csum);
    k_c2<<<32, 256, 0, stream>>>(cb, c2f);
    k_init<<<512, 256, 0, stream>>>(z, resid, quant);

    for (int q = 0; q < NQ; ++q) {
        const float* cbq = cb + (size_t)q * KCODES * D;
        k_argmin<<<NPTS / TM, 256, 0, stream>>>(cbq, c2f + q * KCODES, resid,
                                                idx + q * NPTS);
        k_update<<<NPTS * 32 / 256, 256, 0, stream>>>(cbq, idx + q * NPTS,
                                                      resid, quant);
    }

    k_out0<<<512, 256, 0, stream>>>(z, quant, out0, csum);
    k_outidx<<<NPTS * NQ / 256, 256, 0, stream>>>(idx, out1);
    k_hist<<<NPTS * NQ / 256, 256, 0, stream>>>(idx, hist);
    k_final<<<1, 256, 0, stream>>>(hist, csum, outs);
}

// Round 2
// 1180.870 us; speedup vs baseline: 5.4951x; 5.4951x over previous
//
#include <hip/hip_runtime.h>
#include <math.h>
#include <stdint.h>

#define D       128
#define KCODES  1024
#define NQ      8
#define BATCH   8
#define SLEN    4096
#define NPTS    (BATCH*SLEN)     /* 32768 */
#define TM      64               /* points per argmin block */

// async global->LDS, 16B per lane (wave-uniform LDS base + lane*16)
typedef __attribute__((address_space(1))) const void GV;
typedef __attribute__((address_space(3))) void LV;
__device__ __forceinline__ void gload16(const void* g, void* l) {
    __builtin_amdgcn_global_load_lds((GV*)g, (LV*)l, 16, 0, 0);
}

// ---------------- zero scratch ----------------
__global__ void k_zero(int* hist, double* csum) {
    int t = blockIdx.x * blockDim.x + threadIdx.x;
    if (t < NQ * KCODES) hist[t] = 0;
    if (t == 0) *csum = 0.0;
}

// ---------------- codebook norms: numpy pairwise fp32 ----------------
__global__ void k_c2(const float* __restrict__ cbs, float* __restrict__ c2f) {
    int i = blockIdx.x * blockDim.x + threadIdx.x;   // 0..8191
    const float* row = cbs + (size_t)i * D;
    float r8[8];
    #pragma unroll
    for (int j = 0; j < 8; ++j) r8[j] = __fmul_rn(row[j], row[j]);
    for (int d = 8; d < 128; d += 8)
        #pragma unroll
        for (int j = 0; j < 8; ++j)
            r8[j] = __fadd_rn(r8[j], __fmul_rn(row[d + j], row[d + j]));
    float s01 = __fadd_rn(r8[0], r8[1]);
    float s23 = __fadd_rn(r8[2], r8[3]);
    float s45 = __fadd_rn(r8[4], r8[5]);
    float s67 = __fadd_rn(r8[6], r8[7]);
    c2f[i] = __fadd_rn(__fadd_rn(s01, s23), __fadd_rn(s45, s67));
}

// ---------------- init: z [B,D,S] -> resid fp32 [n][d]; quant = 0 ----------------
__global__ __launch_bounds__(256) void k_init(const float* __restrict__ z,
                                              float* __restrict__ resid,
                                              float* __restrict__ quant) {
    __shared__ float xt[64][129];
    int b = blockIdx.x >> 6, st = blockIdx.x & 63;
    int s0 = st * 64;
    for (int it = 0; it < 32; ++it) {
        int flat = it * 256 + threadIdx.x;
        int d = flat >> 6, sl = flat & 63;
        xt[sl][d] = z[((size_t)(b * D + d)) * SLEN + s0 + sl];
    }
    __syncthreads();
    for (int it = 0; it < 8; ++it) {
        int flat = it * 256 + threadIdx.x;
        int sl = flat >> 5, dq = (flat & 31) * 4;
        size_t o = (size_t)(b * SLEN + s0 + sl) * D + dq;
        float4 r;
        r.x = xt[sl][dq]; r.y = xt[sl][dq + 1];
        r.z = xt[sl][dq + 2]; r.w = xt[sl][dq + 3];
        *(float4*)(resid + o) = r;
        float4 zz; zz.x = zz.y = zz.z = zz.w = 0.0f;
        *(float4*)(quant + o) = zz;
    }
}

// ---------------- fp32-emulated argmin (matches numpy/BLAS rounding) ----------------
// Barrier-free wave-private schedule. 4 waves; wave w owns codes [256w,256w+256)
// in 4 chunks of 64. Lanes: pl=l&7 (point group), cl=l>>3 (code group).
// Tile 8 pts x 8 codes per thread (acc[8][8]). K sliced 16 dims/step.
// Staging: global_load_lds (async DMA, zero staging regs) into a per-wave
// 2x4KB double buffer. LDS image is XOR-swizzled (row r, unit p holds global
// dim-chunk p ^ ((r>>1)&3)) achieved by PRE-SWIZZLING the per-lane global
// source address (LDS dest stays linear: base + lane*16). cf ds_read_b128
// then hits 8 distinct 16B bank columns -> conflict-free.
// Pipeline: issue slice t+1 loads, s_waitcnt vmcnt(4) (slice t arrived,
// t+1 stays in flight), compute slice t. No barriers in main loop.
// Exact fp32 semantics: per (point,code) single FMA chain over dims 0..127
// ascending; score fl(fl(xx - 2*acc) + cc); first-min (strict <, k asc).
__global__ __launch_bounds__(256) void k_argmin(const float* __restrict__ cb,
                                                const float* __restrict__ c2,
                                                const float* __restrict__ resid,
                                                int* __restrict__ idx_out) {
    __shared__ __align__(16) float xs[TM][132];     // 33,792 B
    __shared__ float xxs[TM];
    __shared__ __align__(16) float cs[4][2][1024];  // 32,768 B: [wave][buf][64c x 16d]
    __shared__ float redS[4][TM];
    __shared__ int   redI[4][TM];

    int tid = threadIdx.x;
    int pbase = blockIdx.x * TM;
    int l = tid & 63, w = tid >> 6;
    int pl = l & 7, cl = l >> 3;

    const char*  cwb = (const char*)cb + ((size_t)w << 17);  // wave's 256 code rows
    const float* c2w = c2 + (w << 8);

    // pre-swizzled per-lane global source offset within one (chunk,slice,g) unit:
    // row l>>2 (+16 per g), fetch dim-chunk (l&3)^tau, tau=((l>>3)&3)==((row>>1)&3)
    int gsrc_lane = ((l >> 2) << 9) + ((((l & 3) ^ ((l >> 3) & 3))) << 4);
    // cf read swizzle: row k'=cl+8j -> tau_row = (cl>>1)&3 (indep of j)
    int rtau = (cl >> 1) & 3;
    char* csw = (char*)&cs[w][0][0];

    // prologue: issue slice 0 (chunk 0, s=0) DMA, overlaps X staging
    {
        const char* src = cwb + gsrc_lane;
        #pragma unroll
        for (int g = 0; g < 4; ++g)
            gload16(src + (g << 13), csw + (g << 10));
    }

    // stage X tile (fp32 residual), coalesced float4
    #pragma unroll
    for (int it = 0; it < 8; ++it) {
        int e = (it * 256 + tid) * 4;
        int p = e >> 7, d = e & 127;
        *(float4*)&xs[p][d] = *(const float4*)(resid + (size_t)(pbase + p) * D + d);
    }
    __syncthreads();

    // xx per point: numpy pairwise n=128 (8-accumulator pattern)
    if (tid < TM) {
        float r8[8];
        #pragma unroll
        for (int j = 0; j < 8; ++j) r8[j] = __fmul_rn(xs[tid][j], xs[tid][j]);
        for (int i = 8; i < 128; i += 8)
            #pragma unroll
            for (int j = 0; j < 8; ++j)
                r8[j] = __fadd_rn(r8[j], __fmul_rn(xs[tid][i + j], xs[tid][i + j]));
        float s01 = __fadd_rn(r8[0], r8[1]);
        float s23 = __fadd_rn(r8[2], r8[3]);
        float s45 = __fadd_rn(r8[4], r8[5]);
        float s67 = __fadd_rn(r8[6], r8[7]);
        xxs[tid] = __fadd_rn(__fadd_rn(s01, s23), __fadd_rn(s45, s67));
    }
    __syncthreads();

    float xxr[8];
    #pragma unroll
    for (int i = 0; i < 8; ++i) xxr[i] = xxs[pl + 8 * i];

    float acc[8][8];
    #pragma unroll
    for (int i = 0; i < 8; ++i)
        #pragma unroll
        for (int j = 0; j < 8; ++j) acc[i][j] = 0.0f;
    float best[8]; int bidx[8];
    #pragma unroll
    for (int i = 0; i < 8; ++i) { best[i] = 3.4e38f; bidx[i] = 0; }

    float cc8[8];
    #pragma unroll 1
    for (int t = 0; t < 32; ++t) {           // t = chunk*8 + slice
        int cblk = t >> 3, s = t & 7, buf = t & 1;
        if (s == 0) {
            #pragma unroll
            for (int j = 0; j < 8; ++j)
                cc8[j] = c2w[(cblk << 6) + cl + (j << 3)];
        }
        if (t < 31) {                        // issue next slice's DMA
            int t2 = t + 1;
            const char* src = cwb + gsrc_lane + ((t2 >> 3) << 15) + ((t2 & 7) << 6);
            char* dst = csw + ((t2 & 1) << 12);
            #pragma unroll
            for (int g = 0; g < 4; ++g)
                gload16(src + (g << 13), dst + (g << 10));
            __builtin_amdgcn_sched_barrier(0);
            asm volatile("s_waitcnt vmcnt(4)" ::: "memory");   // slice t arrived
        } else {
            asm volatile("s_waitcnt vmcnt(0)" ::: "memory");
        }
        // compute slice t from buf: 4 d4-steps x 256 FMA
        const char* cbuf = csw + (buf << 12) + (cl << 6);
        const char* xrow = (const char*)&xs[0][0] + pl * 528 + (s << 6);
        #pragma unroll
        for (int d4 = 0; d4 < 4; ++d4) {
            float4 xf[8], cf[8];
            #pragma unroll
            for (int i = 0; i < 8; ++i)
                xf[i] = *(const float4*)(xrow + i * 4224 + (d4 << 4));
            #pragma unroll
            for (int j = 0; j < 8; ++j)
                cf[j] = *(const float4*)(cbuf + ((d4 ^ rtau) << 4) + (j << 9));
            #pragma unroll
            for (int j = 0; j < 8; ++j)
                #pragma unroll
                for (int i = 0; i < 8; ++i) {
                    acc[i][j] = __fmaf_rn(xf[i].x, cf[j].x, acc[i][j]);
                    acc[i][j] = __fmaf_rn(xf[i].y, cf[j].y, acc[i][j]);
                    acc[i][j] = __fmaf_rn(xf[i].z, cf[j].z, acc[i][j]);
                    acc[i][j] = __fmaf_rn(xf[i].w, cf[j].w, acc[i][j]);
                }
        }
        if (s == 7) {                        // end of chunk: fold scores
            #pragma unroll
            for (int j = 0; j < 8; ++j) {
                float cc = cc8[j];
                int k = (w << 8) + (cblk << 6) + cl + (j << 3);
                #pragma unroll
                for (int i = 0; i < 8; ++i) {
                    float t1  = __fadd_rn(xxr[i],
                                          __fmul_rn(-2.0f, acc[i][j]));
                    float dsc = __fadd_rn(t1, cc);
                    if (dsc < best[i]) { best[i] = dsc; bidx[i] = k; }  // k ascending
                    acc[i][j] = 0.0f;
                }
            }
        }
    }

    // cross-lane (cl bits 3..5) lexicographic argmin reduce, then cross-wave
    #pragma unroll
    for (int i = 0; i < 8; ++i) {
        float b = best[i]; int bi = bidx[i];
        #pragma unroll
        for (int off = 8; off < 64; off <<= 1) {
            float b2 = __shfl_xor(b, off, 64);
            int  bi2 = __shfl_xor(bi, off, 64);
            if (b2 < b || (b2 == b && bi2 < bi)) { b = b2; bi = bi2; }
        }
        if (cl == 0) { redS[w][pl + 8 * i] = b; redI[w][pl + 8 * i] = bi; }
    }
    __syncthreads();
    if (tid < TM) {
        float b = redS[0][tid]; int bi = redI[0][tid];
        #pragma unroll
        for (int ww = 1; ww < 4; ++ww) {
            float b2 = redS[ww][tid]; int bi2 = redI[ww][tid];
            if (b2 < b || (b2 == b && bi2 < bi)) { b = b2; bi = bi2; }
        }
        idx_out[pbase + tid] = bi;
    }
}

// ---------------- residual/quant update (fp32, exact np order) ----------------
__global__ void k_update(const float* __restrict__ cb, const int* __restrict__ idx,
                         float* __restrict__ resid, float* __restrict__ quant) {
    int gid = blockIdx.x * blockDim.x + threadIdx.x;   // NPTS*32
    int n = gid >> 5, d4 = (gid & 31) * 4;
    int k = idx[n];
    float4 c = *(const float4*)(cb + (size_t)k * D + d4);
    size_t o = (size_t)n * D + d4;
    float4 r = *(const float4*)(resid + o);
    float4 q = *(const float4*)(quant + o);
    r.x = __fsub_rn(r.x, c.x); r.y = __fsub_rn(r.y, c.y);
    r.z = __fsub_rn(r.z, c.z); r.w = __fsub_rn(r.w, c.w);
    q.x = __fadd_rn(q.x, c.x); q.y = __fadd_rn(q.y, c.y);
    q.z = __fadd_rn(q.z, c.z); q.w = __fadd_rn(q.w, c.w);
    *(float4*)(resid + o) = r;
    *(float4*)(quant + o) = q;
}

// ---------------- out0 = fl(z + fl(q - z)) transposed; commitment partial ----------------
__global__ __launch_bounds__(256) void k_out0(const float* __restrict__ z,
                                              const float* __restrict__ quant,
                                              float* __restrict__ out0,
                                              double* __restrict__ csum) {
    __shared__ float xt[64][129];
    __shared__ double wsum[4];
    int b = blockIdx.x >> 6, st = blockIdx.x & 63;
    int s0 = st * 64;
    for (int it = 0; it < 8; ++it) {
        int flat = it * 256 + threadIdx.x;
        int sl = flat >> 5, dq = (flat & 31) * 4;
        float4 q = *(const float4*)(quant + (size_t)(b * SLEN + s0 + sl) * D + dq);
        xt[sl][dq] = q.x; xt[sl][dq + 1] = q.y;
        xt[sl][dq + 2] = q.z; xt[sl][dq + 3] = q.w;
    }
    __syncthreads();
    double v = 0.0;
    for (int it = 0; it < 32; ++it) {
        int flat = it * 256 + threadIdx.x;
        int d = flat >> 6, sl = flat & 63;
        size_t o = ((size_t)(b * D + d)) * SLEN + s0 + sl;
        float zz = z[o], qq = xt[sl][d];
        out0[o] = __fadd_rn(zz, __fsub_rn(qq, zz));
        float e = __fsub_rn(zz, qq);
        v += (double)e * (double)e;
    }
    for (int off = 32; off > 0; off >>= 1) v += __shfl_down(v, off, 64);
    int lane = threadIdx.x & 63, wv = threadIdx.x >> 6;
    if (lane == 0) wsum[wv] = v;
    __syncthreads();
    if (threadIdx.x == 0) {
        double tsum = wsum[0] + wsum[1] + wsum[2] + wsum[3];
        atomicAdd(csum, tsum);
    }
}

// ---------------- indices output as float ----------------
__global__ void k_outidx(const int* __restrict__ idx, float* __restrict__ out1) {
    int o = blockIdx.x * blockDim.x + threadIdx.x;   // NPTS*NQ
    int q = o & 7, n = o >> 3;
    out1[o] = (float)idx[q * NPTS + n];
}

// ---------------- histogram ----------------
__global__ void k_hist(const int* __restrict__ idx, int* __restrict__ hist) {
    int o = blockIdx.x * blockDim.x + threadIdx.x;   // NQ*NPTS (layout [q][n])
    int q = o >> 15;
    atomicAdd(&hist[q * KCODES + idx[o]], 1);
}

// ---------------- final scalars ----------------
__global__ __launch_bounds__(256) void k_final(const int* __restrict__ hist,
                                               const double* __restrict__ csum,
                                               float* __restrict__ outs) {
    __shared__ double sh[256];
    double perp = 0.0;
    for (int q = 0; q < NQ; ++q) {
        double h = 0.0;
        for (int k = threadIdx.x; k < KCODES; k += 256) {
            double p = (double)hist[q * KCODES + k] / (double)NPTS;
            h -= p * log(p + 1e-10);
        }
        sh[threadIdx.x] = h; __syncthreads();
        for (int off = 128; off > 0; off >>= 1) {
            if (threadIdx.x < off) sh[threadIdx.x] += sh[threadIdx.x + off];
            __syncthreads();
        }
        if (threadIdx.x == 0) perp += exp(sh[0]);
        __syncthreads();
    }
    if (threadIdx.x == 0) {
        outs[0] = (float)(*csum / (double)((size_t)NPTS * D));
        outs[1] = (float)(perp / (double)NQ);
    }
}

extern "C" void kernel_launch(void* const* d_in, const int* in_sizes, int n_in,
                              void* d_out, int out_size, void* d_ws, size_t ws_size,
                              hipStream_t stream) {
    const float* z  = (const float*)d_in[0];
    const float* cb = (const float*)d_in[1];
    float* out0 = (float*)d_out;                 // 4,194,304 floats [B,D,S]
    float* out1 = out0 + 4194304;                // 262,144 floats  [B,S,Q]
    float* outs = out1 + 262144;                 // 2 scalars

    char* w = (char*)d_ws;
    float* resid  = (float*)w;                           // 16,777,216 B
    float* quant  = (float*)(w + 16777216);              // 16,777,216 B
    int*   idx    = (int*)(w + 33554432);                //  1,048,576 B
    int*   hist   = (int*)(w + 34603008);                //     32,768 B
    double* csum  = (double*)(w + 34635776);             //         64 B
    float* c2f    = (float*)(w + 34635840);              //     32,768 B

    k_zero<<<32, 256, 0, stream>>>(hist, csum);
    k_c2<<<32, 256, 0, stream>>>(cb, c2f);
    k_init<<<512, 256, 0, stream>>>(z, resid, quant);

    for (int q = 0; q < NQ; ++q) {
        const float* cbq = cb + (size_t)q * KCODES * D;
        k_argmin<<<NPTS / TM, 256, 0, stream>>>(cbq, c2f + q * KCODES, resid,
                                                idx + q * NPTS);
        k_update<<<NPTS * 32 / 256, 256, 0, stream>>>(cbq, idx + q * NPTS,
                                                      resid, quant);
    }

    k_out0<<<512, 256, 0, stream>>>(z, quant, out0, csum);
    k_outidx<<<NPTS * NQ / 256, 256, 0, stream>>>(idx, out1);
    k_hist<<<NPTS * NQ / 256, 256, 0, stream>>>(idx, hist);
    k_final<<<1, 256, 0, stream>>>(hist, csum, outs);
}